// Round 6
// baseline (354.299 us; speedup 1.0000x reference)
//
#include <hip/hip_runtime.h>
#include <hip/hip_bf16.h>
#include <hip/hip_fp8.h>

#define NN 100000        // nodes
#define NE 3200000       // edges
#define FF 32            // node features
#define LL 50            // node labels
#define ELB 10           // edge labels
#define KK 16            // out dim

#define CH 4096          // edges per p1 block
#define NBLK_P1 782      // ceil(NE/CH)
#define NBUK 391         // ceil(NN/256) buckets of 256 nodes
#define CAP 9216         // slots per bucket (mean 8184, +11 sigma)

typedef float floatx2 __attribute__((ext_vector_type(2)));

__device__ __forceinline__ float fast_tanh(float x) {
    float e = __expf(2.0f * x);
    return 1.0f - 2.0f / (e + 1.0f);   // saturates correctly at +/-1
}

// ---------- phase 1: x->fp8 convert + bucket scatter of u32 recs ----------
// rec u32 = src(17b)<<12 | elab(4b)<<8 | dst_local(8b)
__global__ __launch_bounds__(256) void p1_scatter(const int* __restrict__ esrc,
                                                  const int* __restrict__ edst,
                                                  const int* __restrict__ elab,
                                                  const float* __restrict__ x,
                                                  unsigned* __restrict__ xb,
                                                  int* __restrict__ cursor,
                                                  unsigned* __restrict__ recs) {
    __shared__ int lcnt[NBUK];
    __shared__ int lbase[NBUK];
    int tid = threadIdx.x;
    // x -> fp8 (independent work folded in; ~4 iterations/thread)
    for (int i = blockIdx.x * 256 + tid; i < NN * FF / 4; i += NBLK_P1 * 256) {
        float4 v = ((const float4*)x)[i];
        __hip_fp8_e4m3 a(v.x), b(v.y), c(v.z), d(v.w);
        xb[i] = (unsigned)a.__x | ((unsigned)b.__x << 8) |
                ((unsigned)c.__x << 16) | ((unsigned)d.__x << 24);
    }
    for (int i = tid; i < NBUK; i += 256) lcnt[i] = 0;
    __syncthreads();
    long e0 = (long)blockIdx.x * CH;
    long rem = NE - e0;
    int cnt = rem < CH ? (int)rem : CH;   // always divisible by 4
    int nq = cnt >> 2;
    const int4* edst4 = (const int4*)(edst + e0);
    const int4* esrc4 = (const int4*)(esrc + e0);
    const int4* elab4 = (const int4*)(elab + e0);
    // pass A: count per bucket
    for (int i = tid; i < nq; i += 256) {
        int4 d = edst4[i];
        atomicAdd(&lcnt[d.x >> 8], 1);
        atomicAdd(&lcnt[d.y >> 8], 1);
        atomicAdd(&lcnt[d.z >> 8], 1);
        atomicAdd(&lcnt[d.w >> 8], 1);
    }
    __syncthreads();
    // pass B: reserve contiguous runs (cursor is relative, zero-init by memset)
    for (int i = tid; i < NBUK; i += 256) {
        int c = lcnt[i];
        lbase[i] = c ? atomicAdd(&cursor[i], c) : 0;
        lcnt[i] = 0;   // reuse as local cursor
    }
    __syncthreads();
    // pass C: place (edst/esrc/elab re-read is L2-hot from pass A)
    for (int i = tid; i < nq; i += 256) {
        int4 s4 = esrc4[i];
        int4 l4 = elab4[i];
        int4 d4 = edst4[i];
#pragma unroll
        for (int k = 0; k < 4; ++k) {
            int s  = (&s4.x)[k];
            int d  = (&d4.x)[k];
            int el = (&l4.x)[k];
            int b = d >> 8;
            int ofs = atomicAdd(&lcnt[b], 1);
            int rel = lbase[b] + ofs;
            if (rel < CAP)   // 11-sigma overflow guard
                recs[b * CAP + rel] =
                    ((unsigned)s << 12) | ((unsigned)el << 8) | (unsigned)(d & 255);
        }
    }
}

// ---------- phase 2: per-bucket (256 nodes) exact CSR + widx resolve ----------
__global__ __launch_bounds__(256) void p2_local(const int* __restrict__ cursor,
                                                const unsigned* __restrict__ recs,
                                                const int* __restrict__ labels,
                                                unsigned* __restrict__ packed,
                                                int* __restrict__ gstart,
                                                int* __restrict__ gcnt) {
    __shared__ int deg[256], loff[256], lcur[256], sc[256], labd[256];
    int b = blockIdx.x, tid = threadIdx.x;
    int base = b * CAP;
    int n = cursor[b];
    if (n > CAP) n = CAP;
    int node = (b << 8) + tid;
    deg[tid] = 0;
    lcur[tid] = 0;
    labd[tid] = (node < NN) ? labels[node] : 0;
    __syncthreads();
    for (int i = tid; i < n; i += 256)
        atomicAdd(&deg[(int)(recs[base + i] & 255)], 1);
    __syncthreads();
    sc[tid] = deg[tid];
    __syncthreads();
    for (int ofs = 1; ofs < 256; ofs <<= 1) {
        int t = (tid >= ofs) ? sc[tid - ofs] : 0;
        __syncthreads();
        sc[tid] += t;
        __syncthreads();
    }
    loff[tid] = sc[tid] - deg[tid];   // exclusive
    if (node < NN) { gstart[node] = base + loff[tid]; gcnt[node] = deg[tid]; }
    __syncthreads();
    // place + resolve widx (labels[src]: divergent gather from 400 KB, L2-hot)
    for (int i = tid; i < n; i += 256) {
        unsigned r = recs[base + i];
        int dl  = (int)(r & 255);
        int el  = (int)((r >> 8) & 15);
        int src = (int)(r >> 12);
        int widx = labels[src] * (LL * ELB) + labd[dl] * ELB + el;
        int ofs = atomicAdd(&lcur[dl], 1);
        packed[base + loff[dl] + ofs] = ((unsigned)widx << 17) | (unsigned)src;
    }
}

// ---------- conv: half-wave per node, 8 lanes/row fp8 gather, 4 edge subgroups ----------
__global__ __launch_bounds__(512) void conv_kernel(const unsigned char* __restrict__ xin,
                                                   unsigned char* __restrict__ hout,
                                                   const int* __restrict__ gstart,
                                                   const int* __restrict__ gcnt,
                                                   const unsigned* __restrict__ packed,
                                                   const float* __restrict__ Wtab,
                                                   const float* __restrict__ bias,
                                                   const int* __restrict__ labels) {
    int tid = threadIdx.x;
    int hw = tid >> 5, lane = tid & 31;
    int node = (blockIdx.x << 4) + hw;   // grid exact: 6250*16 = 100000
    int eg = lane >> 3;          // edge subgroup 0..3
    int fg = (lane & 7) << 2;    // feature byte offset 0..28
    int i   = gstart[node] + eg;
    int end = gstart[node] + gcnt[node];
    float4 acc = {0.f, 0.f, 0.f, 0.f};
    // 4x pipelined: 4 packed loads -> 4 w + 4 row loads -> 8 cvt + 16 fma
    for (; i + 12 < end; i += 16) {
        unsigned p0 = packed[i];
        unsigned p1 = packed[i + 4];
        unsigned p2 = packed[i + 8];
        unsigned p3 = packed[i + 12];
        float w0 = Wtab[p0 >> 17], w1 = Wtab[p1 >> 17];
        float w2 = Wtab[p2 >> 17], w3 = Wtab[p3 >> 17];
        unsigned v0 = *(const unsigned*)(xin + ((p0 & 0x1FFFFu) << 5) + fg);
        unsigned v1 = *(const unsigned*)(xin + ((p1 & 0x1FFFFu) << 5) + fg);
        unsigned v2 = *(const unsigned*)(xin + ((p2 & 0x1FFFFu) << 5) + fg);
        unsigned v3 = *(const unsigned*)(xin + ((p3 & 0x1FFFFu) << 5) + fg);
        floatx2 lo, hi;
        lo = __builtin_amdgcn_cvt_pk_f32_fp8((int)v0, false);
        hi = __builtin_amdgcn_cvt_pk_f32_fp8((int)v0, true);
        acc.x += w0 * lo.x; acc.y += w0 * lo.y; acc.z += w0 * hi.x; acc.w += w0 * hi.y;
        lo = __builtin_amdgcn_cvt_pk_f32_fp8((int)v1, false);
        hi = __builtin_amdgcn_cvt_pk_f32_fp8((int)v1, true);
        acc.x += w1 * lo.x; acc.y += w1 * lo.y; acc.z += w1 * hi.x; acc.w += w1 * hi.y;
        lo = __builtin_amdgcn_cvt_pk_f32_fp8((int)v2, false);
        hi = __builtin_amdgcn_cvt_pk_f32_fp8((int)v2, true);
        acc.x += w2 * lo.x; acc.y += w2 * lo.y; acc.z += w2 * hi.x; acc.w += w2 * hi.y;
        lo = __builtin_amdgcn_cvt_pk_f32_fp8((int)v3, false);
        hi = __builtin_amdgcn_cvt_pk_f32_fp8((int)v3, true);
        acc.x += w3 * lo.x; acc.y += w3 * lo.y; acc.z += w3 * hi.x; acc.w += w3 * hi.y;
    }
    for (; i < end; i += 4) {
        unsigned p = packed[i];
        float w = Wtab[p >> 17];
        unsigned v = *(const unsigned*)(xin + ((p & 0x1FFFFu) << 5) + fg);
        floatx2 lo = __builtin_amdgcn_cvt_pk_f32_fp8((int)v, false);
        floatx2 hi = __builtin_amdgcn_cvt_pk_f32_fp8((int)v, true);
        acc.x += w * lo.x; acc.y += w * lo.y; acc.z += w * hi.x; acc.w += w * hi.y;
    }
    // reduce across the 4 edge subgroups (lane bits 3,4)
    acc.x += __shfl_xor(acc.x, 8);  acc.y += __shfl_xor(acc.y, 8);
    acc.z += __shfl_xor(acc.z, 8);  acc.w += __shfl_xor(acc.w, 8);
    acc.x += __shfl_xor(acc.x, 16); acc.y += __shfl_xor(acc.y, 16);
    acc.z += __shfl_xor(acc.z, 16); acc.w += __shfl_xor(acc.w, 16);
    if (lane < 8) {
        float bb = bias[labels[node]];
        __hip_fp8_e4m3 q0(fast_tanh(acc.x + bb));
        __hip_fp8_e4m3 q1(fast_tanh(acc.y + bb));
        __hip_fp8_e4m3 q2(fast_tanh(acc.z + bb));
        __hip_fp8_e4m3 q3(fast_tanh(acc.w + bb));
        unsigned pk = (unsigned)q0.__x | ((unsigned)q1.__x << 8) |
                      ((unsigned)q2.__x << 16) | ((unsigned)q3.__x << 24);
        ((unsigned*)(hout + ((long)node << 5)))[lane] = pk;   // lane == fg/4
    }
}

// ---------- fused label pooling + resize ----------
__global__ __launch_bounds__(256) void lsum_resize_kernel(const unsigned* __restrict__ h,
                                                          const int* __restrict__ labels,
                                                          float* __restrict__ sums,
                                                          int* __restrict__ done,
                                                          const float* __restrict__ Wr,
                                                          const float* __restrict__ br,
                                                          float* __restrict__ out) {
    __shared__ float ls[LL * FF];
    __shared__ int winner;
    int tid = threadIdx.x;
    for (int i = tid; i < LL * FF; i += 256) ls[i] = 0.f;
    __syncthreads();
    for (int i = blockIdx.x * 256 + tid; i < NN * 8; i += gridDim.x * 256) {
        unsigned pv = h[i];
        int nodei = i >> 3;
        int fb = (i & 7) << 2;
        int l = labels[nodei];
        floatx2 lo = __builtin_amdgcn_cvt_pk_f32_fp8((int)pv, false);
        floatx2 hi = __builtin_amdgcn_cvt_pk_f32_fp8((int)pv, true);
        float* bp = &ls[l * FF + fb];
        atomicAdd(bp + 0, lo.x);
        atomicAdd(bp + 1, lo.y);
        atomicAdd(bp + 2, hi.x);
        atomicAdd(bp + 3, hi.y);
    }
    __syncthreads();
    for (int i = tid; i < LL * FF; i += 256) atomicAdd(&sums[i], ls[i]);
    __threadfence();
    if (tid == 0) winner = (atomicAdd(done, 1) == (int)gridDim.x - 1) ? 1 : 0;
    __syncthreads();
    if (!winner) return;
    // ---- winner block: resize. Read sums via device-scope atomic (coherent). ----
    __shared__ float red[256][KK];
    float acc[KK];
#pragma unroll
    for (int k = 0; k < KK; ++k) acc[k] = 0.f;
    for (int p = tid; p < LL * FF; p += 256) {
        float sv = atomicAdd(&sums[p], 0.0f);   // coherent read of other blocks' adds
#pragma unroll
        for (int k = 0; k < KK; ++k) acc[k] += sv * Wr[p * KK + k];
    }
#pragma unroll
    for (int k = 0; k < KK; ++k) red[tid][k] = acc[k];
    __syncthreads();
    for (int sft = 128; sft > 0; sft >>= 1) {
        if (tid < sft) {
#pragma unroll
            for (int k = 0; k < KK; ++k) red[tid][k] += red[tid + sft][k];
        }
        __syncthreads();
    }
    if (tid < KK) out[tid] = fast_tanh(red[0][tid] + br[tid]);
}

extern "C" void kernel_launch(void* const* d_in, const int* in_sizes, int n_in,
                              void* d_out, int out_size, void* d_ws, size_t ws_size,
                              hipStream_t stream) {
    const float* x   = (const float*)d_in[0];
    const float* W1  = (const float*)d_in[1];
    const float* b1  = (const float*)d_in[2];
    const float* W2  = (const float*)d_in[3];
    const float* b2  = (const float*)d_in[4];
    const float* W3  = (const float*)d_in[5];
    const float* b3  = (const float*)d_in[6];
    const float* Wr  = (const float*)d_in[7];
    const float* br  = (const float*)d_in[8];
    const int* labels = (const int*)d_in[9];
    const int* esrc   = (const int*)d_in[10];
    const int* edst   = (const int*)d_in[11];
    const int* elab   = (const int*)d_in[12];
    float* out = (float*)d_out;

    char* ws = (char*)d_ws;
    size_t o = 0;
    auto alloc = [&](size_t bytes) -> void* {
        void* p = ws + o;
        o += (bytes + 255) & ~(size_t)255;
        return p;
    };
    // regionA: recs (14.4 MB) reused for h1/h2 (fp8, 3.2 MB each) after p2
    char* regionA = (char*)alloc((size_t)NBUK * CAP * sizeof(unsigned));
    unsigned* recs = (unsigned*)regionA;
    unsigned char* h1 = (unsigned char*)regionA;
    unsigned char* h2 = (unsigned char*)(regionA + (size_t)NN * FF);

    unsigned* packed = (unsigned*)alloc((size_t)NBUK * CAP * sizeof(unsigned));
    unsigned* xb     = (unsigned*)alloc((size_t)NN * FF);          // fp8 x
    int* cursor = (int*)alloc(NBUK * sizeof(int));
    float* sums = (float*)alloc(LL * FF * sizeof(float));
    int* done   = (int*)alloc(sizeof(int));
    int* gstart = (int*)alloc(NN * sizeof(int));
    int* gcnt   = (int*)alloc(NN * sizeof(int));
    // total ~33 MB of d_ws

    // single memset zeroes cursor + sums + done (contiguous in alloc order)
    size_t msz = (size_t)((char*)done - (char*)cursor) + sizeof(int);
    hipMemsetAsync(cursor, 0, msz, stream);

    p1_scatter<<<NBLK_P1, 256, 0, stream>>>(esrc, edst, elab, x, xb, cursor, recs);
    p2_local<<<NBUK, 256, 0, stream>>>(cursor, recs, labels, packed, gstart, gcnt);

    conv_kernel<<<NN / 16, 512, 0, stream>>>((const unsigned char*)xb, h1, gstart, gcnt, packed, W1, b1, labels);
    conv_kernel<<<NN / 16, 512, 0, stream>>>(h1, h2, gstart, gcnt, packed, W2, b2, labels);
    conv_kernel<<<NN / 16, 512, 0, stream>>>(h2, h1, gstart, gcnt, packed, W3, b3, labels);

    lsum_resize_kernel<<<128, 256, 0, stream>>>((const unsigned*)h1, labels, sums, done, Wr, br, out);
}

// Round 7
// 321.837 us; speedup vs baseline: 1.1009x; 1.1009x over previous
//
#include <hip/hip_runtime.h>
#include <hip/hip_bf16.h>
#include <hip/hip_fp8.h>

#define NN 100000        // nodes
#define NE 3200000       // edges
#define FF 32            // node features
#define LL 50            // node labels
#define ELB 10           // edge labels
#define KK 16            // out dim

#define CH 8192          // edges per p1 block
#define NBLK_P1 391      // ceil(NE/CH)
#define NBUK 196         // ceil(NN/512) buckets of 512 nodes
#define CAP 18432        // slots per bucket (mean 16384, +16 sigma)

typedef float floatx2 __attribute__((ext_vector_type(2)));

__device__ __forceinline__ float fast_tanh(float x) {
    float e = __expf(2.0f * x);
    return 1.0f - 2.0f / (e + 1.0f);   // saturates correctly at +/-1
}

// ---------- phase 1: x->fp8 convert + bucket scatter of u32 recs ----------
// rec u32 = src(17b)<<13 | elab(4b)<<9 | dst_local(9b)    [R5 config: 46 us measured]
__global__ __launch_bounds__(512) void p1_scatter(const int* __restrict__ esrc,
                                                  const int* __restrict__ edst,
                                                  const int* __restrict__ elab,
                                                  const float* __restrict__ x,
                                                  unsigned* __restrict__ xb,
                                                  int* __restrict__ cursor,
                                                  unsigned* __restrict__ recs) {
    __shared__ int lcnt[NBUK];
    __shared__ int lbase[NBUK];
    int tid = threadIdx.x;
    // x -> fp8 (independent work folded in; ~4 iterations/thread)
    for (int i = blockIdx.x * 512 + tid; i < NN * FF / 4; i += NBLK_P1 * 512) {
        float4 v = ((const float4*)x)[i];
        __hip_fp8_e4m3 a(v.x), b(v.y), c(v.z), d(v.w);
        xb[i] = (unsigned)a.__x | ((unsigned)b.__x << 8) |
                ((unsigned)c.__x << 16) | ((unsigned)d.__x << 24);
    }
    for (int i = tid; i < NBUK; i += 512) lcnt[i] = 0;
    __syncthreads();
    long e0 = (long)blockIdx.x * CH;
    long rem = NE - e0;
    int cnt = rem < CH ? (int)rem : CH;   // always divisible by 4
    int nq = cnt >> 2;
    const int4* edst4 = (const int4*)(edst + e0);
    const int4* esrc4 = (const int4*)(esrc + e0);
    const int4* elab4 = (const int4*)(elab + e0);
    // pass A: count per bucket
    for (int i = tid; i < nq; i += 512) {
        int4 d = edst4[i];
        atomicAdd(&lcnt[d.x >> 9], 1);
        atomicAdd(&lcnt[d.y >> 9], 1);
        atomicAdd(&lcnt[d.z >> 9], 1);
        atomicAdd(&lcnt[d.w >> 9], 1);
    }
    __syncthreads();
    // pass B: reserve contiguous runs (cursor is relative, zero-init by memset)
    for (int i = tid; i < NBUK; i += 512) {
        int c = lcnt[i];
        lbase[i] = c ? atomicAdd(&cursor[i], c) : 0;
        lcnt[i] = 0;   // reuse as local cursor
    }
    __syncthreads();
    // pass C: place (edst re-read is L2-hot from pass A)
    for (int i = tid; i < nq; i += 512) {
        int4 s4 = esrc4[i];
        int4 l4 = elab4[i];
        int4 d4 = edst4[i];
#pragma unroll
        for (int k = 0; k < 4; ++k) {
            int s  = (&s4.x)[k];
            int d  = (&d4.x)[k];
            int el = (&l4.x)[k];
            int b = d >> 9;
            int ofs = atomicAdd(&lcnt[b], 1);
            int rel = lbase[b] + ofs;
            if (rel < CAP)   // 16-sigma overflow guard
                recs[b * CAP + rel] =
                    ((unsigned)s << 13) | ((unsigned)el << 9) | (unsigned)(d & 511);
        }
    }
}

// ---------- phase 2: per-bucket (512 nodes) exact CSR + widx resolve ----------
__global__ __launch_bounds__(512) void p2_local(const int* __restrict__ cursor,
                                                const unsigned* __restrict__ recs,
                                                const int* __restrict__ labels,
                                                unsigned* __restrict__ packed,
                                                int* __restrict__ gstart,
                                                int* __restrict__ gcnt) {
    __shared__ int deg[512], loff[512], lcur[512], sc[512], labd[512];
    int b = blockIdx.x, tid = threadIdx.x;
    int base = b * CAP;
    int n = cursor[b];
    if (n > CAP) n = CAP;
    int node = (b << 9) + tid;
    deg[tid] = 0;
    lcur[tid] = 0;
    labd[tid] = (node < NN) ? labels[node] : 0;
    __syncthreads();
    for (int i = tid; i < n; i += 512)
        atomicAdd(&deg[(int)(recs[base + i] & 511)], 1);
    __syncthreads();
    sc[tid] = deg[tid];
    __syncthreads();
    for (int ofs = 1; ofs < 512; ofs <<= 1) {
        int t = (tid >= ofs) ? sc[tid - ofs] : 0;
        __syncthreads();
        sc[tid] += t;
        __syncthreads();
    }
    loff[tid] = sc[tid] - deg[tid];   // exclusive
    if (node < NN) { gstart[node] = base + loff[tid]; gcnt[node] = deg[tid]; }
    __syncthreads();
    // place + resolve widx (labels[src]: divergent gather from 400 KB, L2-hot)
    for (int i = tid; i < n; i += 512) {
        unsigned r = recs[base + i];
        int dl  = (int)(r & 511);
        int el  = (int)((r >> 9) & 15);
        int src = (int)(r >> 13);
        int widx = labels[src] * (LL * ELB) + labd[dl] * ELB + el;
        int ofs = atomicAdd(&lcur[dl], 1);
        packed[base + loff[dl] + ofs] = ((unsigned)widx << 17) | (unsigned)src;
    }
}

// ---------- conv: half-wave per node, LDS-staged broadcast, fp8 gather (R4 version) ----------
__global__ __launch_bounds__(256) void conv_kernel(const unsigned char* __restrict__ xin,
                                                   unsigned char* __restrict__ hout,
                                                   const int* __restrict__ gstart,
                                                   const int* __restrict__ gcnt,
                                                   const unsigned* __restrict__ packed,
                                                   const float* __restrict__ Wtab,
                                                   const float* __restrict__ bias,
                                                   const int* __restrict__ labels) {
    __shared__ unsigned stage[8][64];   // per half-wave: 32 x (w_bits, src*32 byte-off)
    int tid = threadIdx.x;
    int hw = tid >> 5, lane = tid & 31;
    int node = (blockIdx.x << 3) + hw;   // grid exact: 12500*8 = 100000
    int s = gstart[node];
    int n = gcnt[node];
    int eg = lane >> 3;          // edge subgroup 0..3
    int fg = (lane & 7) << 2;    // feature byte offset 0..28
    float4 acc = {0.f, 0.f, 0.f, 0.f};
    for (int base = 0; base < n; base += 32) {
        float w = 0.f;
        unsigned so = 0u;
        int idx = base + lane;
        if (idx < n) {
            unsigned p = packed[s + idx];
            w = Wtab[p >> 17];
            so = (p & 0x1FFFFu) << 5;   // src * 32 bytes (fp8 row)
        }
        ((uint2*)&stage[hw][0])[lane] = make_uint2(__float_as_uint(w), so);
        __builtin_amdgcn_wave_barrier();   // same-wave DS RAW: DS pipe in-order
#pragma unroll
        for (int j = 0; j < 8; ++j) {
            uint2 ws = ((const uint2*)&stage[hw][0])[j * 4 + eg];
            unsigned pv = *(const unsigned*)(xin + ws.y + fg);   // 4 fp8 feats
            floatx2 lo = __builtin_amdgcn_cvt_pk_f32_fp8((int)pv, false);
            floatx2 hi = __builtin_amdgcn_cvt_pk_f32_fp8((int)pv, true);
            float we = __uint_as_float(ws.x);
            acc.x += we * lo.x;
            acc.y += we * lo.y;
            acc.z += we * hi.x;
            acc.w += we * hi.y;
        }
        __builtin_amdgcn_wave_barrier();
    }
    // reduce across the 4 edge subgroups (lane bits 3,4)
    acc.x += __shfl_xor(acc.x, 8);  acc.y += __shfl_xor(acc.y, 8);
    acc.z += __shfl_xor(acc.z, 8);  acc.w += __shfl_xor(acc.w, 8);
    acc.x += __shfl_xor(acc.x, 16); acc.y += __shfl_xor(acc.y, 16);
    acc.z += __shfl_xor(acc.z, 16); acc.w += __shfl_xor(acc.w, 16);
    if (lane < 8) {
        float bb = bias[labels[node]];
        __hip_fp8_e4m3 q0(fast_tanh(acc.x + bb));
        __hip_fp8_e4m3 q1(fast_tanh(acc.y + bb));
        __hip_fp8_e4m3 q2(fast_tanh(acc.z + bb));
        __hip_fp8_e4m3 q3(fast_tanh(acc.w + bb));
        unsigned pk = (unsigned)q0.__x | ((unsigned)q1.__x << 8) |
                      ((unsigned)q2.__x << 16) | ((unsigned)q3.__x << 24);
        ((unsigned*)(hout + ((long)node << 5)))[lane] = pk;   // lane == fg/4
    }
}

// ---------- fused label pooling + resize ----------
__global__ __launch_bounds__(256) void lsum_resize_kernel(const unsigned* __restrict__ h,
                                                          const int* __restrict__ labels,
                                                          float* __restrict__ sums,
                                                          int* __restrict__ done,
                                                          const float* __restrict__ Wr,
                                                          const float* __restrict__ br,
                                                          float* __restrict__ out) {
    __shared__ float ls[LL * FF];
    __shared__ int winner;
    int tid = threadIdx.x;
    for (int i = tid; i < LL * FF; i += 256) ls[i] = 0.f;
    __syncthreads();
    for (int i = blockIdx.x * 256 + tid; i < NN * 8; i += gridDim.x * 256) {
        unsigned pv = h[i];
        int nodei = i >> 3;
        int fb = (i & 7) << 2;
        int l = labels[nodei];
        floatx2 lo = __builtin_amdgcn_cvt_pk_f32_fp8((int)pv, false);
        floatx2 hi = __builtin_amdgcn_cvt_pk_f32_fp8((int)pv, true);
        float* bp = &ls[l * FF + fb];
        atomicAdd(bp + 0, lo.x);
        atomicAdd(bp + 1, lo.y);
        atomicAdd(bp + 2, hi.x);
        atomicAdd(bp + 3, hi.y);
    }
    __syncthreads();
    for (int i = tid; i < LL * FF; i += 256) atomicAdd(&sums[i], ls[i]);
    __threadfence();
    if (tid == 0) winner = (atomicAdd(done, 1) == (int)gridDim.x - 1) ? 1 : 0;
    __syncthreads();
    if (!winner) return;
    // ---- winner block: resize. Read sums via device-scope atomic (coherent). ----
    __shared__ float red[256][KK];
    float acc[KK];
#pragma unroll
    for (int k = 0; k < KK; ++k) acc[k] = 0.f;
    for (int p = tid; p < LL * FF; p += 256) {
        float sv = atomicAdd(&sums[p], 0.0f);   // coherent read of other blocks' adds
#pragma unroll
        for (int k = 0; k < KK; ++k) acc[k] += sv * Wr[p * KK + k];
    }
#pragma unroll
    for (int k = 0; k < KK; ++k) red[tid][k] = acc[k];
    __syncthreads();
    for (int sft = 128; sft > 0; sft >>= 1) {
        if (tid < sft) {
#pragma unroll
            for (int k = 0; k < KK; ++k) red[tid][k] += red[tid + sft][k];
        }
        __syncthreads();
    }
    if (tid < KK) out[tid] = fast_tanh(red[0][tid] + br[tid]);
}

extern "C" void kernel_launch(void* const* d_in, const int* in_sizes, int n_in,
                              void* d_out, int out_size, void* d_ws, size_t ws_size,
                              hipStream_t stream) {
    const float* x   = (const float*)d_in[0];
    const float* W1  = (const float*)d_in[1];
    const float* b1  = (const float*)d_in[2];
    const float* W2  = (const float*)d_in[3];
    const float* b2  = (const float*)d_in[4];
    const float* W3  = (const float*)d_in[5];
    const float* b3  = (const float*)d_in[6];
    const float* Wr  = (const float*)d_in[7];
    const float* br  = (const float*)d_in[8];
    const int* labels = (const int*)d_in[9];
    const int* esrc   = (const int*)d_in[10];
    const int* edst   = (const int*)d_in[11];
    const int* elab   = (const int*)d_in[12];
    float* out = (float*)d_out;

    char* ws = (char*)d_ws;
    size_t o = 0;
    auto alloc = [&](size_t bytes) -> void* {
        void* p = ws + o;
        o += (bytes + 255) & ~(size_t)255;
        return p;
    };
    // regionA: recs (14.45 MB) reused for h1/h2 (fp8, 3.2 MB each) after p2
    char* regionA = (char*)alloc((size_t)NBUK * CAP * sizeof(unsigned));
    unsigned* recs = (unsigned*)regionA;
    unsigned char* h1 = (unsigned char*)regionA;
    unsigned char* h2 = (unsigned char*)(regionA + (size_t)NN * FF);

    unsigned* packed = (unsigned*)alloc((size_t)NBUK * CAP * sizeof(unsigned));
    unsigned* xb     = (unsigned*)alloc((size_t)NN * FF);          // fp8 x
    int* cursor = (int*)alloc(NBUK * sizeof(int));
    float* sums = (float*)alloc(LL * FF * sizeof(float));
    int* done   = (int*)alloc(sizeof(int));
    int* gstart = (int*)alloc(NN * sizeof(int));
    int* gcnt   = (int*)alloc(NN * sizeof(int));
    // total ~33 MB of d_ws

    // single memset zeroes cursor + sums + done (contiguous in alloc order)
    size_t msz = (size_t)((char*)done - (char*)cursor) + sizeof(int);
    hipMemsetAsync(cursor, 0, msz, stream);

    p1_scatter<<<NBLK_P1, 512, 0, stream>>>(esrc, edst, elab, x, xb, cursor, recs);
    p2_local<<<NBUK, 512, 0, stream>>>(cursor, recs, labels, packed, gstart, gcnt);

    conv_kernel<<<NN / 8, 256, 0, stream>>>((const unsigned char*)xb, h1, gstart, gcnt, packed, W1, b1, labels);
    conv_kernel<<<NN / 8, 256, 0, stream>>>(h1, h2, gstart, gcnt, packed, W2, b2, labels);
    conv_kernel<<<NN / 8, 256, 0, stream>>>(h2, h1, gstart, gcnt, packed, W3, b3, labels);

    lsum_resize_kernel<<<128, 256, 0, stream>>>((const unsigned*)h1, labels, sums, done, Wr, br, out);
}

// Round 9
// 319.084 us; speedup vs baseline: 1.1104x; 1.0086x over previous
//
#include <hip/hip_runtime.h>
#include <hip/hip_bf16.h>
#include <hip/hip_fp8.h>

#define NN 100000        // nodes
#define NE 3200000       // edges
#define FF 32            // node features
#define LL 50            // node labels
#define ELB 10           // edge labels
#define KK 16            // out dim

#define CH 8192          // edges per p1 block
#define NBLK_P1 391      // ceil(NE/CH)
#define NBUK 196         // ceil(NN/512) buckets of 512 nodes
#define CAP 18432        // slots per bucket (mean 16384, +16 sigma)

#define LSB 256          // lsum blocks (1 per CU; 102 KB LDS each)

typedef float floatx2 __attribute__((ext_vector_type(2)));

__device__ __forceinline__ float fast_tanh(float x) {
    float e = __expf(2.0f * x);
    return 1.0f - 2.0f / (e + 1.0f);   // saturates correctly at +/-1
}

// ---------- phase 1: x->fp8 convert + bucket scatter of u32 recs ----------
// rec u32 = src(17b)<<13 | elab(4b)<<9 | dst_local(9b)    [R5 config: 46 us measured]
__global__ __launch_bounds__(512) void p1_scatter(const int* __restrict__ esrc,
                                                  const int* __restrict__ edst,
                                                  const int* __restrict__ elab,
                                                  const float* __restrict__ x,
                                                  unsigned* __restrict__ xb,
                                                  int* __restrict__ cursor,
                                                  unsigned* __restrict__ recs) {
    __shared__ int lcnt[NBUK];
    __shared__ int lbase[NBUK];
    int tid = threadIdx.x;
    // x -> fp8 (independent work folded in; ~4 iterations/thread)
    for (int i = blockIdx.x * 512 + tid; i < NN * FF / 4; i += NBLK_P1 * 512) {
        float4 v = ((const float4*)x)[i];
        __hip_fp8_e4m3 a(v.x), b(v.y), c(v.z), d(v.w);
        xb[i] = (unsigned)a.__x | ((unsigned)b.__x << 8) |
                ((unsigned)c.__x << 16) | ((unsigned)d.__x << 24);
    }
    for (int i = tid; i < NBUK; i += 512) lcnt[i] = 0;
    __syncthreads();
    long e0 = (long)blockIdx.x * CH;
    long rem = NE - e0;
    int cnt = rem < CH ? (int)rem : CH;   // always divisible by 4
    int nq = cnt >> 2;
    const int4* edst4 = (const int4*)(edst + e0);
    const int4* esrc4 = (const int4*)(esrc + e0);
    const int4* elab4 = (const int4*)(elab + e0);
    // pass A: count per bucket
    for (int i = tid; i < nq; i += 512) {
        int4 d = edst4[i];
        atomicAdd(&lcnt[d.x >> 9], 1);
        atomicAdd(&lcnt[d.y >> 9], 1);
        atomicAdd(&lcnt[d.z >> 9], 1);
        atomicAdd(&lcnt[d.w >> 9], 1);
    }
    __syncthreads();
    // pass B: reserve contiguous runs (cursor is relative, zero-init by memset)
    for (int i = tid; i < NBUK; i += 512) {
        int c = lcnt[i];
        lbase[i] = c ? atomicAdd(&cursor[i], c) : 0;
        lcnt[i] = 0;   // reuse as local cursor
    }
    __syncthreads();
    // pass C: place (edst re-read is L2-hot from pass A)
    for (int i = tid; i < nq; i += 512) {
        int4 s4 = esrc4[i];
        int4 l4 = elab4[i];
        int4 d4 = edst4[i];
#pragma unroll
        for (int k = 0; k < 4; ++k) {
            int s  = (&s4.x)[k];
            int d  = (&d4.x)[k];
            int el = (&l4.x)[k];
            int b = d >> 9;
            int ofs = atomicAdd(&lcnt[b], 1);
            int rel = lbase[b] + ofs;
            if (rel < CAP)   // 16-sigma overflow guard
                recs[b * CAP + rel] =
                    ((unsigned)s << 13) | ((unsigned)el << 9) | (unsigned)(d & 511);
        }
    }
}

// ---------- phase 2: per-bucket (512 nodes) exact CSR + widx resolve ----------
__global__ __launch_bounds__(512) void p2_local(const int* __restrict__ cursor,
                                                const unsigned* __restrict__ recs,
                                                const int* __restrict__ labels,
                                                unsigned* __restrict__ packed,
                                                int* __restrict__ gstart,
                                                int* __restrict__ gcnt) {
    __shared__ int deg[512], loff[512], lcur[512], sc[512], labd[512];
    int b = blockIdx.x, tid = threadIdx.x;
    int base = b * CAP;
    int n = cursor[b];
    if (n > CAP) n = CAP;
    int node = (b << 9) + tid;
    deg[tid] = 0;
    lcur[tid] = 0;
    labd[tid] = (node < NN) ? labels[node] : 0;
    __syncthreads();
    for (int i = tid; i < n; i += 512)
        atomicAdd(&deg[(int)(recs[base + i] & 511)], 1);
    __syncthreads();
    sc[tid] = deg[tid];
    __syncthreads();
    for (int ofs = 1; ofs < 512; ofs <<= 1) {
        int t = (tid >= ofs) ? sc[tid - ofs] : 0;
        __syncthreads();
        sc[tid] += t;
        __syncthreads();
    }
    loff[tid] = sc[tid] - deg[tid];   // exclusive
    if (node < NN) { gstart[node] = base + loff[tid]; gcnt[node] = deg[tid]; }
    __syncthreads();
    // place + resolve widx (labels[src]: divergent gather from 400 KB, L2-hot)
    for (int i = tid; i < n; i += 512) {
        unsigned r = recs[base + i];
        int dl  = (int)(r & 511);
        int el  = (int)((r >> 9) & 15);
        int src = (int)(r >> 13);
        int widx = labels[src] * (LL * ELB) + labd[dl] * ELB + el;
        int ofs = atomicAdd(&lcur[dl], 1);
        packed[base + loff[dl] + ofs] = ((unsigned)widx << 17) | (unsigned)src;
    }
}

// ---------- conv: half-wave per node, LDS-staged broadcast, fp8 gather ----------
__global__ __launch_bounds__(256) void conv_kernel(const unsigned char* __restrict__ xin,
                                                   unsigned char* __restrict__ hout,
                                                   const int* __restrict__ gstart,
                                                   const int* __restrict__ gcnt,
                                                   const unsigned* __restrict__ packed,
                                                   const float* __restrict__ Wtab,
                                                   const float* __restrict__ bias,
                                                   const int* __restrict__ labels) {
    __shared__ unsigned stage[8][64];   // per half-wave: 32 x (w_bits, src*32 byte-off)
    int tid = threadIdx.x;
    int hw = tid >> 5, lane = tid & 31;
    int node = (blockIdx.x << 3) + hw;   // grid exact: 12500*8 = 100000
    int s = gstart[node];
    int n = gcnt[node];
    int eg = lane >> 3;          // edge subgroup 0..3
    int fg = (lane & 7) << 2;    // feature byte offset 0..28
    float4 acc = {0.f, 0.f, 0.f, 0.f};
    for (int base = 0; base < n; base += 32) {
        float w = 0.f;
        unsigned so = 0u;
        int idx = base + lane;
        if (idx < n) {
            unsigned p = packed[s + idx];
            w = Wtab[p >> 17];
            so = (p & 0x1FFFFu) << 5;   // src * 32 bytes (fp8 row)
        }
        ((uint2*)&stage[hw][0])[lane] = make_uint2(__float_as_uint(w), so);
        __builtin_amdgcn_wave_barrier();   // same-wave DS RAW: DS pipe in-order
#pragma unroll
        for (int j = 0; j < 8; ++j) {
            uint2 ws = ((const uint2*)&stage[hw][0])[j * 4 + eg];
            unsigned pv = *(const unsigned*)(xin + ws.y + fg);   // 4 fp8 feats
            floatx2 lo = __builtin_amdgcn_cvt_pk_f32_fp8((int)pv, false);
            floatx2 hi = __builtin_amdgcn_cvt_pk_f32_fp8((int)pv, true);
            float we = __uint_as_float(ws.x);
            acc.x += we * lo.x;
            acc.y += we * lo.y;
            acc.z += we * hi.x;
            acc.w += we * hi.y;
        }
        __builtin_amdgcn_wave_barrier();
    }
    // reduce across the 4 edge subgroups (lane bits 3,4)
    acc.x += __shfl_xor(acc.x, 8);  acc.y += __shfl_xor(acc.y, 8);
    acc.z += __shfl_xor(acc.z, 8);  acc.w += __shfl_xor(acc.w, 8);
    acc.x += __shfl_xor(acc.x, 16); acc.y += __shfl_xor(acc.y, 16);
    acc.z += __shfl_xor(acc.z, 16); acc.w += __shfl_xor(acc.w, 16);
    if (lane < 8) {
        float bb = bias[labels[node]];
        __hip_fp8_e4m3 q0(fast_tanh(acc.x + bb));
        __hip_fp8_e4m3 q1(fast_tanh(acc.y + bb));
        __hip_fp8_e4m3 q2(fast_tanh(acc.z + bb));
        __hip_fp8_e4m3 q3(fast_tanh(acc.w + bb));
        unsigned pk = (unsigned)q0.__x | ((unsigned)q1.__x << 8) |
                      ((unsigned)q2.__x << 16) | ((unsigned)q3.__x << 24);
        ((unsigned*)(hout + ((long)node << 5)))[lane] = pk;   // lane == fg/4
    }
}

// ---------- fused label pooling + resize: atomic-free hot loop ----------
// 16 half-waves/block, each with a PRIVATE ls[50][32] copy (102 KB LDS total).
// lane = feature; one node per half-wave iteration; plain LDS rmw (no atomics).
__global__ __launch_bounds__(512, 1) void lsum_resize_kernel(
        const unsigned* __restrict__ h32,
        const int* __restrict__ labels,
        const float* __restrict__ Wr,
        const float* __restrict__ br,
        float* __restrict__ outacc,
        int* __restrict__ done,
        float* __restrict__ out) {
    __shared__ float ls[16][LL * FF];
    __shared__ float po[KK];
    __shared__ int winner;
    int tid = threadIdx.x;
    int hw = tid >> 5, lane = tid & 31;
    for (int i = tid; i < 16 * LL * FF; i += 512) ((float*)ls)[i] = 0.f;
    if (tid < KK) po[tid] = 0.f;
    __syncthreads();
    int widx = lane >> 2;          // dword within 32B row
    int bsh  = (lane & 3) << 3;    // byte shift within dword
    float* myls = &ls[hw][0];
    for (int node = blockIdx.x * 16 + hw; node < NN; node += LSB * 16) {
        unsigned wv = h32[node * 8 + widx];                       // 2 lanes/addr bcast
        floatx2 vv = __builtin_amdgcn_cvt_pk_f32_fp8((int)(wv >> bsh), false);
        float v = vv.x;
        int l = labels[node];                                     // uniform in half-wave
        myls[l * FF + lane] += v;   // banks = lane: conflict-free
    }
    __syncthreads();
    // fused 16-copy sum + Wr contraction into per-thread pk[16]
    float pk[KK];
#pragma unroll
    for (int k = 0; k < KK; ++k) pk[k] = 0.f;
    for (int e = tid; e < LL * FF; e += 512) {
        float s = 0.f;
#pragma unroll
        for (int c = 0; c < 16; ++c) s += ls[c][e];
        const float* wr = Wr + e * KK;
#pragma unroll
        for (int k = 0; k < KK; ++k) pk[k] += s * wr[k];
    }
    // wave reduction (64 lanes)
#pragma unroll
    for (int k = 0; k < KK; ++k) {
        pk[k] += __shfl_xor(pk[k], 1);
        pk[k] += __shfl_xor(pk[k], 2);
        pk[k] += __shfl_xor(pk[k], 4);
        pk[k] += __shfl_xor(pk[k], 8);
        pk[k] += __shfl_xor(pk[k], 16);
        pk[k] += __shfl_xor(pk[k], 32);
    }
    if ((tid & 63) == 0) {
#pragma unroll
        for (int k = 0; k < KK; ++k) atomicAdd(&po[k], pk[k]);   // 8 waves -> LDS
    }
    __syncthreads();
    if (tid < KK) atomicAdd(&outacc[tid], po[tid]);              // 16 per block
    __threadfence();
    __syncthreads();
    if (tid == 0) winner = (atomicAdd(done, 1) == LSB - 1) ? 1 : 0;
    __syncthreads();
    if (winner && tid < KK)
        out[tid] = fast_tanh(atomicAdd(&outacc[tid], 0.0f) + br[tid]);
}

extern "C" void kernel_launch(void* const* d_in, const int* in_sizes, int n_in,
                              void* d_out, int out_size, void* d_ws, size_t ws_size,
                              hipStream_t stream) {
    const float* x   = (const float*)d_in[0];
    const float* W1  = (const float*)d_in[1];
    const float* b1  = (const float*)d_in[2];
    const float* W2  = (const float*)d_in[3];
    const float* b2  = (const float*)d_in[4];
    const float* W3  = (const float*)d_in[5];
    const float* b3  = (const float*)d_in[6];
    const float* Wr  = (const float*)d_in[7];
    const float* br  = (const float*)d_in[8];
    const int* labels = (const int*)d_in[9];
    const int* esrc   = (const int*)d_in[10];
    const int* edst   = (const int*)d_in[11];
    const int* elab   = (const int*)d_in[12];
    float* out = (float*)d_out;

    char* ws = (char*)d_ws;
    size_t o = 0;
    auto alloc = [&](size_t bytes) -> void* {
        void* p = ws + o;
        o += (bytes + 255) & ~(size_t)255;
        return p;
    };
    // regionA: recs (14.45 MB) reused for h1/h2 (fp8, 3.2 MB each) after p2
    char* regionA = (char*)alloc((size_t)NBUK * CAP * sizeof(unsigned));
    unsigned* recs = (unsigned*)regionA;
    unsigned char* h1 = (unsigned char*)regionA;
    unsigned char* h2 = (unsigned char*)(regionA + (size_t)NN * FF);

    unsigned* packed = (unsigned*)alloc((size_t)NBUK * CAP * sizeof(unsigned));
    unsigned* xb     = (unsigned*)alloc((size_t)NN * FF);          // fp8 x
    int* cursor   = (int*)alloc(NBUK * sizeof(int));
    float* outacc = (float*)alloc(KK * sizeof(float));
    int* done     = (int*)alloc(sizeof(int));
    int* gstart   = (int*)alloc(NN * sizeof(int));
    int* gcnt     = (int*)alloc(NN * sizeof(int));
    // total ~33 MB of d_ws

    // single memset zeroes cursor + outacc + done (contiguous in alloc order)
    size_t msz = (size_t)((char*)done - (char*)cursor) + sizeof(int);
    (void)hipMemsetAsync(cursor, 0, msz, stream);

    p1_scatter<<<NBLK_P1, 512, 0, stream>>>(esrc, edst, elab, x, xb, cursor, recs);
    p2_local<<<NBUK, 512, 0, stream>>>(cursor, recs, labels, packed, gstart, gcnt);

    conv_kernel<<<NN / 8, 256, 0, stream>>>((const unsigned char*)xb, h1, gstart, gcnt, packed, W1, b1, labels);
    conv_kernel<<<NN / 8, 256, 0, stream>>>(h1, h2, gstart, gcnt, packed, W2, b2, labels);
    conv_kernel<<<NN / 8, 256, 0, stream>>>(h2, h1, gstart, gcnt, packed, W3, b3, labels);

    lsum_resize_kernel<<<LSB, 512, 0, stream>>>((const unsigned*)h1, labels, Wr, br,
                                                outacc, done, out);
}